// Round 10
// baseline (78.392 us; speedup 1.0000x reference)
//
#include <hip/hip_runtime.h>

// Problem constants (from reference): B=8, N=4096, D=3
#define B_ 8
#define N_ 4096
#define P_ 8                            // own points per lane
#define OWN_PER_BLOCK (64 * P_)         // 512
#define OWN_CHUNKS (N_ / OWN_PER_BLOCK) // 8
#define OPP_CHUNKS 16                   // opposite range split across blocks
#define OPP_SLICE (N_ / OPP_CHUNKS)     // 256 opp points per block
#define OPP_PER_WAVE (OPP_SLICE / 4)    // 64
#define N_COLS (2 * B_ * OWN_CHUNKS)    // 128 (dir,b,own-chunk) columns

// Pair-eval of opp points A,B against own point i: 6 FMA + min3-fusable mins.
#define EVAL_PAIR(QA, QB, PX, PY, PZ, M) do { \
    float ea = fmaf((QA).z, PZ, (QA).w); ea = fmaf((QA).y, PY, ea); ea = fmaf((QA).x, PX, ea); \
    float eb = fmaf((QB).z, PZ, (QB).w); eb = fmaf((QB).y, PY, eb); eb = fmaf((QB).x, PX, eb); \
    M = fminf(M, fminf(ea, eb)); \
} while (0)

// dir 0: own = y (j), opp = x -> acc[0]  (min over axis 1, mask x_mask)
// dir 1: own = x (i), opp = y -> acc[1]  (min over axis 2, mask y_mask)
// Grid (OWN_CHUNKS, B_*OPP_CHUNKS, 2) = 8*128*2 = 2048 blocks, 256 threads.
// Fully fused: LDS-staged dot-form opp slice -> FMA/min hot loop -> partial
// write -> per-column counter: 16th block of a column does the masked f64
// reduction; 128th column writes the final scalar. One kernel launch.
__global__ __launch_bounds__(256, 8) void chamfer_fused_kernel(
        const float* __restrict__ x, const float* __restrict__ y,
        const float* __restrict__ xm, const float* __restrict__ ym,
        float* __restrict__ part, double* __restrict__ acc,
        unsigned* __restrict__ gcnt, unsigned* __restrict__ ccnt,
        float* __restrict__ out) {
    const int dir  = blockIdx.z;
    const int b    = blockIdx.y >> 4;
    const int oc   = blockIdx.y & 15;
    const int base = blockIdx.x * OWN_PER_BLOCK;

    const float* own = dir ? x : y;
    const float* opp = dir ? y : x;

    const int t = threadIdx.x;
    const int l = t & 63;
    const int su = __builtin_amdgcn_readfirstlane(t >> 6);  // wave id

    // Stage opp slice into LDS in dot form: (-2qx, -2qy, -2qz, |q|^2).
    __shared__ float4 sq[OPP_SLICE];       // 4 KB
    {
        const float* ob = opp + ((size_t)b * N_ + oc * OPP_SLICE) * 3;
        const float a = ob[3 * t], bb = ob[3 * t + 1], c = ob[3 * t + 2];
        sq[t] = make_float4(-2.f * a, -2.f * bb, -2.f * c,
                            a * a + bb * bb + c * c);
    }

    // Per-lane own points (coalesced 12 B/lane per group of 64).
    const float* op0 = own + ((size_t)b * N_ + base + l) * 3;
    const float px0 = op0[0],    py0 = op0[1],    pz0 = op0[2];
    const float px1 = op0[192],  py1 = op0[193],  pz1 = op0[194];
    const float px2 = op0[384],  py2 = op0[385],  pz2 = op0[386];
    const float px3 = op0[576],  py3 = op0[577],  pz3 = op0[578];
    const float px4 = op0[768],  py4 = op0[769],  pz4 = op0[770];
    const float px5 = op0[960],  py5 = op0[961],  pz5 = op0[962];
    const float px6 = op0[1152], py6 = op0[1153], pz6 = op0[1154];
    const float px7 = op0[1344], py7 = op0[1345], pz7 = op0[1346];

    __syncthreads();

    float m0 = 1e30f, m1 = 1e30f, m2 = 1e30f, m3 = 1e30f;
    float m4 = 1e30f, m5 = 1e30f, m6 = 1e30f, m7 = 1e30f;

    // Hot loop: wave su scans its 64-pt quarter via broadcast ds_read_b128.
    // Pairs of opp points -> fminf(m, fminf(ea,eb)) fuses to v_min3_f32 and
    // decouples the m-chain. 7 inst / 2 evals.
    const float4* qs = &sq[su * OPP_PER_WAVE];
#pragma unroll 2
    for (int k = 0; k < OPP_PER_WAVE; k += 2) {
        const float4 qA = qs[k];
        const float4 qB = qs[k + 1];
        EVAL_PAIR(qA, qB, px0, py0, pz0, m0);
        EVAL_PAIR(qA, qB, px1, py1, pz1, m1);
        EVAL_PAIR(qA, qB, px2, py2, pz2, m2);
        EVAL_PAIR(qA, qB, px3, py3, pz3, m3);
        EVAL_PAIR(qA, qB, px4, py4, pz4, m4);
        EVAL_PAIR(qA, qB, px5, py5, pz5, m5);
        EVAL_PAIR(qA, qB, px6, py6, pz6, m6);
        EVAL_PAIR(qA, qB, px7, py7, pz7, m7);
    }

    // d^2 = min_e + |p|^2; cross-wave min; coalesced partial writes.
    __shared__ float red[4][OWN_PER_BLOCK]; // 8 KB
    red[su][l]       = m0 + (px0 * px0 + py0 * py0 + pz0 * pz0);
    red[su][64 + l]  = m1 + (px1 * px1 + py1 * py1 + pz1 * pz1);
    red[su][128 + l] = m2 + (px2 * px2 + py2 * py2 + pz2 * pz2);
    red[su][192 + l] = m3 + (px3 * px3 + py3 * py3 + pz3 * pz3);
    red[su][256 + l] = m4 + (px4 * px4 + py4 * py4 + pz4 * pz4);
    red[su][320 + l] = m5 + (px5 * px5 + py5 * py5 + pz5 * pz5);
    red[su][384 + l] = m6 + (px6 * px6 + py6 * py6 + pz6 * pz6);
    red[su][448 + l] = m7 + (px7 * px7 + py7 * py7 + pz7 * pz7);
    __syncthreads();

    const size_t colbase = (((size_t)dir * B_ + b) * OPP_CHUNKS) * N_ + base;
    {
        float* pr = part + colbase + (size_t)oc * N_;
#pragma unroll
        for (int k = 0; k < 2; ++k) {
            const int i = k * 256 + t;
            pr[i] = fminf(fminf(red[0][i], red[1][i]),
                          fminf(red[2][i], red[3][i]));
        }
    }

    // Column completion: 16th block of this (dir,b,own-chunk) column reduces.
    __shared__ int lastFlag;
    if (t == 0) {
        __threadfence();  // release partial writes before counter bump
        const int colid = (dir * B_ + b) * OWN_CHUNKS + blockIdx.x;
        lastFlag = (atomicAdd(&ccnt[colid], 1u) == OPP_CHUNKS - 1);
    }
    __syncthreads();

    if (lastFlag) {
        __threadfence();  // acquire other blocks' partial writes
        const float* msk = dir ? ym : xm;
        double val = 0.0;
#pragma unroll
        for (int k = 0; k < 2; ++k) {
            const int i = k * 256 + t;
            float mn = 1e30f;
#pragma unroll
            for (int c = 0; c < OPP_CHUNKS; ++c) {
                volatile const float* vp = part + colbase + (size_t)c * N_ + i;
                mn = fminf(mn, *vp);
            }
            val += (double)(msk[(size_t)b * N_ + base + i] * mn);
        }
        for (int off = 32; off; off >>= 1)
            val += __shfl_down(val, off);
        if (l == 0)
            atomicAdd(&acc[dir], val);

        __syncthreads();
        if (t == 0) {
            __threadfence();  // release acc adds before global counter bump
            unsigned old = atomicAdd(gcnt, 1u);
            if (old == N_COLS - 1) {
                __threadfence();  // acquire all columns' acc adds
                volatile const double* va = acc;
                double d = (va[0] - va[1]) / (double)(B_ * N_);
                out[0] = (float)(d * d);
            }
        }
    }
}

extern "C" void kernel_launch(void* const* d_in, const int* in_sizes, int n_in,
                              void* d_out, int out_size, void* d_ws, size_t ws_size,
                              hipStream_t stream) {
    const float* x  = (const float*)d_in[0];
    const float* y  = (const float*)d_in[1];
    const float* xm = (const float*)d_in[2];
    const float* ym = (const float*)d_in[3];
    float* out = (float*)d_out;

    // ws layout: [0,16) acc f64x2; [16,20) gcnt; [64,576) ccnt[128]; 4KB-aligned part.
    double*   acc  = (double*)d_ws;
    unsigned* gcnt = (unsigned*)((char*)d_ws + 16);
    unsigned* ccnt = (unsigned*)((char*)d_ws + 64);
    float*    prt  = (float*)((char*)d_ws + 4096);          // 2*8*16*4096*4 = 4 MB

    // Zero counters + accumulators (graph-capturable async memset).
    hipMemsetAsync(d_ws, 0, 4096, stream);

    dim3 grid(OWN_CHUNKS, B_ * OPP_CHUNKS, 2);              // 2048 blocks
    chamfer_fused_kernel<<<grid, 256, 0, stream>>>(x, y, xm, ym,
                                                   prt, acc, gcnt, ccnt, out);
}

// Round 11
// 78.289 us; speedup vs baseline: 1.0013x; 1.0013x over previous
//
#include <hip/hip_runtime.h>

// Problem constants (from reference): B=8, N=4096, D=3
#define B_ 8
#define N_ 4096
#define P_ 8                            // own points per lane
#define OWN_PER_BLOCK (64 * P_)         // 512
#define OWN_CHUNKS (N_ / OWN_PER_BLOCK) // 8
#define OPP_CHUNKS 16                   // opposite range split across blocks
#define OPP_SLICE (N_ / OPP_CHUNKS)     // 256 opp points per block
#define OPP_PER_WAVE (OPP_SLICE / 4)    // 64
#define N_COLS (2 * B_ * OWN_CHUNKS)    // 128 (dir,b,own-chunk) columns

// Round-9 proven hot-loop form: one opp point q = (-2qx,-2qy,-2qz,|q|^2),
// e = |q|^2 - 2 q.p, 3 FMA + 1 min per own point, all-VGPR operands.
#define EVAL_Q(Q) do { \
    float e0 = fmaf((Q).z, pz0, (Q).w); e0 = fmaf((Q).y, py0, e0); e0 = fmaf((Q).x, px0, e0); m0 = fminf(m0, e0); \
    float e1 = fmaf((Q).z, pz1, (Q).w); e1 = fmaf((Q).y, py1, e1); e1 = fmaf((Q).x, px1, e1); m1 = fminf(m1, e1); \
    float e2 = fmaf((Q).z, pz2, (Q).w); e2 = fmaf((Q).y, py2, e2); e2 = fmaf((Q).x, px2, e2); m2 = fminf(m2, e2); \
    float e3 = fmaf((Q).z, pz3, (Q).w); e3 = fmaf((Q).y, py3, e3); e3 = fmaf((Q).x, px3, e3); m3 = fminf(m3, e3); \
    float e4 = fmaf((Q).z, pz4, (Q).w); e4 = fmaf((Q).y, py4, e4); e4 = fmaf((Q).x, px4, e4); m4 = fminf(m4, e4); \
    float e5 = fmaf((Q).z, pz5, (Q).w); e5 = fmaf((Q).y, py5, e5); e5 = fmaf((Q).x, px5, e5); m5 = fminf(m5, e5); \
    float e6 = fmaf((Q).z, pz6, (Q).w); e6 = fmaf((Q).y, py6, e6); e6 = fmaf((Q).x, px6, e6); m6 = fminf(m6, e6); \
    float e7 = fmaf((Q).z, pz7, (Q).w); e7 = fmaf((Q).y, py7, e7); e7 = fmaf((Q).x, px7, e7); m7 = fminf(m7, e7); \
} while (0)

// dir 0: own = y (j), opp = x -> acc[0]  (min over axis 1, mask x_mask)
// dir 1: own = x (i), opp = y -> acc[1]  (min over axis 2, mask y_mask)
// Grid (OWN_CHUNKS, B_*OPP_CHUNKS, 2) = 2048 blocks, 256 threads.
// Fused: LDS-staged dot-form opp slice -> FMA/min hot loop -> partial write
// -> per-column counter tail: 16th block of a column does the masked f64
// reduction; 128th column writes the final scalar. One kernel launch.
__global__ __launch_bounds__(256, 8) void chamfer_fused_kernel(
        const float* __restrict__ x, const float* __restrict__ y,
        const float* __restrict__ xm, const float* __restrict__ ym,
        float* __restrict__ part, double* __restrict__ acc,
        unsigned* __restrict__ gcnt, unsigned* __restrict__ ccnt,
        float* __restrict__ out) {
    const int dir  = blockIdx.z;
    const int b    = blockIdx.y >> 4;
    const int oc   = blockIdx.y & 15;
    const int base = blockIdx.x * OWN_PER_BLOCK;

    const float* own = dir ? x : y;
    const float* opp = dir ? y : x;

    const int t = threadIdx.x;
    const int l = t & 63;
    const int su = __builtin_amdgcn_readfirstlane(t >> 6);  // wave id

    // Stage opp slice into LDS in dot form: (-2qx, -2qy, -2qz, |q|^2).
    __shared__ float4 sq[OPP_SLICE];       // 4 KB
    {
        const float* ob = opp + ((size_t)b * N_ + oc * OPP_SLICE) * 3;
        const float a = ob[3 * t], bb = ob[3 * t + 1], c = ob[3 * t + 2];
        sq[t] = make_float4(-2.f * a, -2.f * bb, -2.f * c,
                            a * a + bb * bb + c * c);
    }

    // Per-lane own points (coalesced 12 B/lane per group of 64).
    const float* op0 = own + ((size_t)b * N_ + base + l) * 3;
    float px0 = op0[0],    py0 = op0[1],    pz0 = op0[2];
    float px1 = op0[192],  py1 = op0[193],  pz1 = op0[194];
    float px2 = op0[384],  py2 = op0[385],  pz2 = op0[386];
    float px3 = op0[576],  py3 = op0[577],  pz3 = op0[578];
    float px4 = op0[768],  py4 = op0[769],  pz4 = op0[770];
    float px5 = op0[960],  py5 = op0[961],  pz5 = op0[962];
    float px6 = op0[1152], py6 = op0[1153], pz6 = op0[1154];
    float px7 = op0[1344], py7 = op0[1345], pz7 = op0[1346];

    // Register pin: make the 24 own coords asm-defined so the allocator can
    // neither rematerialize the global loads inside the hot loop nor sink
    // them — the round-10 regression (VGPR=32, VALUBusy 30%) mechanism.
    asm volatile("" : "+v"(px0), "+v"(py0), "+v"(pz0),
                      "+v"(px1), "+v"(py1), "+v"(pz1),
                      "+v"(px2), "+v"(py2), "+v"(pz2),
                      "+v"(px3), "+v"(py3), "+v"(pz3),
                      "+v"(px4), "+v"(py4), "+v"(pz4),
                      "+v"(px5), "+v"(py5), "+v"(pz5),
                      "+v"(px6), "+v"(py6), "+v"(pz6),
                      "+v"(px7), "+v"(py7), "+v"(pz7));

    __syncthreads();

    float m0 = 1e30f, m1 = 1e30f, m2 = 1e30f, m3 = 1e30f;
    float m4 = 1e30f, m5 = 1e30f, m6 = 1e30f, m7 = 1e30f;

    // Hot loop (round-9 form): wave su scans its 64-pt quarter via broadcast
    // ds_read_b128; 32 VALU per ds_read keeps the LDS pipe under VALU.
    const float4* qs = &sq[su * OPP_PER_WAVE];
#pragma unroll 4
    for (int k = 0; k < OPP_PER_WAVE; ++k) {
        const float4 q = qs[k];
        EVAL_Q(q);
    }

    // d^2 = min_e + |p|^2; cross-wave min; coalesced partial writes.
    __shared__ float red[4][OWN_PER_BLOCK]; // 8 KB
    red[su][l]       = m0 + (px0 * px0 + py0 * py0 + pz0 * pz0);
    red[su][64 + l]  = m1 + (px1 * px1 + py1 * py1 + pz1 * pz1);
    red[su][128 + l] = m2 + (px2 * px2 + py2 * py2 + pz2 * pz2);
    red[su][192 + l] = m3 + (px3 * px3 + py3 * py3 + pz3 * pz3);
    red[su][256 + l] = m4 + (px4 * px4 + py4 * py4 + pz4 * pz4);
    red[su][320 + l] = m5 + (px5 * px5 + py5 * py5 + pz5 * pz5);
    red[su][384 + l] = m6 + (px6 * px6 + py6 * py6 + pz6 * pz6);
    red[su][448 + l] = m7 + (px7 * px7 + py7 * py7 + pz7 * pz7);
    __syncthreads();

    const size_t colbase = (((size_t)dir * B_ + b) * OPP_CHUNKS) * N_ + base;
    {
        float* pr = part + colbase + (size_t)oc * N_;
#pragma unroll
        for (int k = 0; k < 2; ++k) {
            const int i = k * 256 + t;
            pr[i] = fminf(fminf(red[0][i], red[1][i]),
                          fminf(red[2][i], red[3][i]));
        }
    }

    // Column completion: 16th block of this (dir,b,own-chunk) column reduces.
    __shared__ int lastFlag;
    if (t == 0) {
        __threadfence();  // release partial writes before counter bump
        const int colid = (dir * B_ + b) * OWN_CHUNKS + blockIdx.x;
        lastFlag = (atomicAdd(&ccnt[colid], 1u) == OPP_CHUNKS - 1);
    }
    __syncthreads();

    if (lastFlag) {
        __threadfence();  // acquire other blocks' partial writes
        const float* msk = dir ? ym : xm;
        double val = 0.0;
#pragma unroll
        for (int k = 0; k < 2; ++k) {
            const int i = k * 256 + t;
            float mn = 1e30f;
#pragma unroll
            for (int c = 0; c < OPP_CHUNKS; ++c) {
                volatile const float* vp = part + colbase + (size_t)c * N_ + i;
                mn = fminf(mn, *vp);
            }
            val += (double)(msk[(size_t)b * N_ + base + i] * mn);
        }
        for (int off = 32; off; off >>= 1)
            val += __shfl_down(val, off);
        if (l == 0)
            atomicAdd(&acc[dir], val);

        __syncthreads();
        if (t == 0) {
            __threadfence();  // release acc adds before global counter bump
            unsigned old = atomicAdd(gcnt, 1u);
            if (old == N_COLS - 1) {
                __threadfence();  // acquire all columns' acc adds
                volatile const double* va = acc;
                double d = (va[0] - va[1]) / (double)(B_ * N_);
                out[0] = (float)(d * d);
            }
        }
    }
}

extern "C" void kernel_launch(void* const* d_in, const int* in_sizes, int n_in,
                              void* d_out, int out_size, void* d_ws, size_t ws_size,
                              hipStream_t stream) {
    const float* x  = (const float*)d_in[0];
    const float* y  = (const float*)d_in[1];
    const float* xm = (const float*)d_in[2];
    const float* ym = (const float*)d_in[3];
    float* out = (float*)d_out;

    // ws layout: [0,16) acc f64x2; [16,20) gcnt; [64,576) ccnt[128]; 4KB-aligned part.
    double*   acc  = (double*)d_ws;
    unsigned* gcnt = (unsigned*)((char*)d_ws + 16);
    unsigned* ccnt = (unsigned*)((char*)d_ws + 64);
    float*    prt  = (float*)((char*)d_ws + 4096);          // 2*8*16*4096*4 = 4 MB

    // Zero counters + accumulators (graph-capturable async memset).
    hipMemsetAsync(d_ws, 0, 4096, stream);

    dim3 grid(OWN_CHUNKS, B_ * OPP_CHUNKS, 2);              // 2048 blocks
    chamfer_fused_kernel<<<grid, 256, 0, stream>>>(x, y, xm, ym,
                                                   prt, acc, gcnt, ccnt, out);
}

// Round 12
// 44.512 us; speedup vs baseline: 1.7611x; 1.7588x over previous
//
#include <hip/hip_runtime.h>

// Problem constants (from reference): B=8, N=4096, D=3
#define B_ 8
#define N_ 4096
#define P_ 8                            // own points per lane
#define OWN_PER_BLOCK (64 * P_)         // 512
#define OWN_CHUNKS (N_ / OWN_PER_BLOCK) // 8
#define OPP_CHUNKS 16                   // opposite range split across blocks
#define OPP_SLICE (N_ / OPP_CHUNKS)     // 256 opp points per block
#define OPP_PER_WAVE (OPP_SLICE / 4)    // 64
#define RED_BLOCKS ((2 * B_ * N_) / 256) // 256

// Pair-eval of opp points A,B against own point i: 6 FMA + v_min3-fusable
// double-min. 56 VALU slots per 2 opp points (vs 66 single-point form).
#define EVAL_PAIR(QA, QB, PX, PY, PZ, M) do { \
    float ea = fmaf((QA).z, PZ, (QA).w); ea = fmaf((QA).y, PY, ea); ea = fmaf((QA).x, PX, ea); \
    float eb = fmaf((QB).z, PZ, (QB).w); eb = fmaf((QB).y, PY, eb); eb = fmaf((QB).x, PX, eb); \
    M = fminf(M, fminf(ea, eb)); \
} while (0)

// dir 0: own = y (j), opp = x -> acc[0]  (min over axis 1)
// dir 1: own = x (i), opp = y -> acc[1]  (min over axis 2)
// Grid (OWN_CHUNKS, B_*OPP_CHUNKS, 2) = 8*128*2 = 2048 blocks = 8 blocks/CU.
// Round-9 structure: LDS-staged dot-form opp slice, broadcast ds_read_b128
// hot loop, partial write. NO device-scope fences here (round-10/11 lesson:
// agent-scope __threadfence in the fat kernel = L2 WB/INV storm, 2x slower).
__global__ __launch_bounds__(256, 8) void chamfer_min_kernel(
        const float* __restrict__ x, const float* __restrict__ y,
        float* __restrict__ part, double* __restrict__ acc,
        unsigned* __restrict__ cnt) {
    const int dir  = blockIdx.z;
    const int b    = blockIdx.y >> 4;
    const int oc   = blockIdx.y & 15;
    const int base = blockIdx.x * OWN_PER_BLOCK;

    const float* own = dir ? x : y;
    const float* opp = dir ? y : x;

    const int t = threadIdx.x;
    const int l = t & 63;
    const int su = __builtin_amdgcn_readfirstlane(t >> 6);  // wave id

    // Zero the f64 accumulators + completion counter (one block; the reduce
    // kernel that consumes them runs strictly after this kernel).
    if (blockIdx.x == 0 && blockIdx.y == 0 && blockIdx.z == 0) {
        if (t < 2) acc[t] = 0.0;
        if (t == 2) *cnt = 0u;
    }

    // Stage opp slice into LDS in dot form: (-2qx, -2qy, -2qz, |q|^2).
    __shared__ float4 sq[OPP_SLICE];       // 4 KB
    {
        const float* ob = opp + ((size_t)b * N_ + oc * OPP_SLICE) * 3;
        const float a = ob[3 * t], bb = ob[3 * t + 1], c = ob[3 * t + 2];
        sq[t] = make_float4(-2.f * a, -2.f * bb, -2.f * c,
                            a * a + bb * bb + c * c);
    }

    // Per-lane own points (coalesced 12 B/lane per group of 64).
    const float* op0 = own + ((size_t)b * N_ + base + l) * 3;
    const float px0 = op0[0],    py0 = op0[1],    pz0 = op0[2];
    const float px1 = op0[192],  py1 = op0[193],  pz1 = op0[194];
    const float px2 = op0[384],  py2 = op0[385],  pz2 = op0[386];
    const float px3 = op0[576],  py3 = op0[577],  pz3 = op0[578];
    const float px4 = op0[768],  py4 = op0[769],  pz4 = op0[770];
    const float px5 = op0[960],  py5 = op0[961],  pz5 = op0[962];
    const float px6 = op0[1152], py6 = op0[1153], pz6 = op0[1154];
    const float px7 = op0[1344], py7 = op0[1345], pz7 = op0[1346];

    __syncthreads();

    float m0 = 1e30f, m1 = 1e30f, m2 = 1e30f, m3 = 1e30f;
    float m4 = 1e30f, m5 = 1e30f, m6 = 1e30f, m7 = 1e30f;

    // Hot loop: wave su scans its 64-pt quarter via broadcast ds_read_b128,
    // two opp points per iteration (min3 fusion).
    const float4* qs = &sq[su * OPP_PER_WAVE];
#pragma unroll 2
    for (int k = 0; k < OPP_PER_WAVE; k += 2) {
        const float4 qA = qs[k];
        const float4 qB = qs[k + 1];
        EVAL_PAIR(qA, qB, px0, py0, pz0, m0);
        EVAL_PAIR(qA, qB, px1, py1, pz1, m1);
        EVAL_PAIR(qA, qB, px2, py2, pz2, m2);
        EVAL_PAIR(qA, qB, px3, py3, pz3, m3);
        EVAL_PAIR(qA, qB, px4, py4, pz4, m4);
        EVAL_PAIR(qA, qB, px5, py5, pz5, m5);
        EVAL_PAIR(qA, qB, px6, py6, pz6, m6);
        EVAL_PAIR(qA, qB, px7, py7, pz7, m7);
    }

    // d^2 = min_e + |p|^2; cross-wave min; coalesced partial writes.
    __shared__ float red[4][OWN_PER_BLOCK]; // 8 KB
    red[su][l]       = m0 + (px0 * px0 + py0 * py0 + pz0 * pz0);
    red[su][64 + l]  = m1 + (px1 * px1 + py1 * py1 + pz1 * pz1);
    red[su][128 + l] = m2 + (px2 * px2 + py2 * py2 + pz2 * pz2);
    red[su][192 + l] = m3 + (px3 * px3 + py3 * py3 + pz3 * pz3);
    red[su][256 + l] = m4 + (px4 * px4 + py4 * py4 + pz4 * pz4);
    red[su][320 + l] = m5 + (px5 * px5 + py5 * py5 + pz5 * pz5);
    red[su][384 + l] = m6 + (px6 * px6 + py6 * py6 + pz6 * pz6);
    red[su][448 + l] = m7 + (px7 * px7 + py7 * py7 + pz7 * pz7);
    __syncthreads();

    float* pr = part + (((size_t)dir * B_ + b) * OPP_CHUNKS + oc) * N_ + base;
#pragma unroll
    for (int k = 0; k < 2; ++k) {
        const int i = k * 256 + t;
        pr[i] = fminf(fminf(red[0][i], red[1][i]), fminf(red[2][i], red[3][i]));
    }
}

// Combine OPP_CHUNKS partials, apply mask, accumulate in f64; the last block
// to finish writes the final scalar (fused finalize). Device-scope fences
// live only here (256 small blocks, after the compute) — proven cheap.
__global__ __launch_bounds__(256) void chamfer_reduce_kernel(
        const float* __restrict__ part,
        const float* __restrict__ xm, const float* __restrict__ ym,
        double* __restrict__ acc, unsigned* __restrict__ cnt,
        float* __restrict__ out) {
    const int id  = blockIdx.x * 256 + threadIdx.x;
    const int dir = id >> 15;            // uniform per wave
    const int rem = id & 32767;
    const int b   = rem >> 12;
    const int n   = rem & (N_ - 1);

    const float* msk = dir ? ym : xm;

    float mn = 1e30f;
#pragma unroll
    for (int oc = 0; oc < OPP_CHUNKS; ++oc)
        mn = fminf(mn, part[(((size_t)dir * B_ + b) * OPP_CHUNKS + oc) * N_ + n]);

    double val = (double)(msk[(size_t)b * N_ + n] * mn);
    for (int off = 32; off; off >>= 1)
        val += __shfl_down(val, off);
    if ((threadIdx.x & 63) == 0)
        atomicAdd(&acc[dir], val);

    __syncthreads();
    if (threadIdx.x == 0) {
        __threadfence();
        unsigned old = atomicAdd(cnt, 1u);
        if (old == RED_BLOCKS - 1) {
            __threadfence();
            volatile const double* va = acc;
            double d = (va[0] - va[1]) / (double)(B_ * N_);
            out[0] = (float)(d * d);
        }
    }
}

extern "C" void kernel_launch(void* const* d_in, const int* in_sizes, int n_in,
                              void* d_out, int out_size, void* d_ws, size_t ws_size,
                              hipStream_t stream) {
    const float* x  = (const float*)d_in[0];
    const float* y  = (const float*)d_in[1];
    const float* xm = (const float*)d_in[2];
    const float* ym = (const float*)d_in[3];
    float* out = (float*)d_out;

    double*   acc = (double*)d_ws;                          // 16 B
    unsigned* cnt = (unsigned*)((char*)d_ws + 16);          // 4 B
    float*    prt = (float*)((char*)d_ws + 256);            // 2*8*16*4096*4 = 4 MB

    dim3 grid(OWN_CHUNKS, B_ * OPP_CHUNKS, 2);              // 2048 blocks
    chamfer_min_kernel<<<grid, 256, 0, stream>>>(x, y, prt, acc, cnt);

    chamfer_reduce_kernel<<<RED_BLOCKS, 256, 0, stream>>>(prt, xm, ym, acc, cnt, out);
}

// Round 13
// 44.374 us; speedup vs baseline: 1.7666x; 1.0031x over previous
//
#include <hip/hip_runtime.h>

// Problem constants (from reference): B=8, N=4096, D=3
#define B_ 8
#define N_ 4096
#define P_ 8                            // own points per lane
#define OWN_PER_BLOCK (64 * P_)         // 512
#define OWN_CHUNKS (N_ / OWN_PER_BLOCK) // 8
#define OPP_CHUNKS 16                   // opposite range split across blocks
#define OPP_SLICE (N_ / OPP_CHUNKS)     // 256 opp points per block
#define OPP_PER_WAVE (OPP_SLICE / 4)    // 64
#define RED_BLOCKS ((2 * B_ * N_) / 256) // 256

// Pair-eval of opp points A,B against own point i: 6 FMA + v_min3-fusable
// double-min.
#define EVAL_PAIR(QA, QB, PX, PY, PZ, M) do { \
    float ea = fmaf((QA).z, PZ, (QA).w); ea = fmaf((QA).y, PY, ea); ea = fmaf((QA).x, PX, ea); \
    float eb = fmaf((QB).z, PZ, (QB).w); eb = fmaf((QB).y, PY, eb); eb = fmaf((QB).x, PX, eb); \
    M = fminf(M, fminf(ea, eb)); \
} while (0)

// dir 0: own = y (j), opp = x -> acc[0]  (min over axis 1)
// dir 1: own = x (i), opp = y -> acc[1]  (min over axis 2)
// Grid (OWN_CHUNKS, B_*OPP_CHUNKS, 2) = 8*128*2 = 2048 blocks = 8 blocks/CU.
// NOTE: plain __launch_bounds__(256) — the (256,8) variant allocated only
// 32 VGPRs (r10/r11 counters), forcing in-loop scratch spills of the 24
// own-point coords (invisible in HBM counters; VALUBusy 28%). ~60 VGPRs
// still permits 8 waves/SIMD.
__global__ __launch_bounds__(256) void chamfer_min_kernel(
        const float* __restrict__ x, const float* __restrict__ y,
        float* __restrict__ part, double* __restrict__ acc,
        unsigned* __restrict__ cnt) {
    const int dir  = blockIdx.z;
    const int b    = blockIdx.y >> 4;
    const int oc   = blockIdx.y & 15;
    const int base = blockIdx.x * OWN_PER_BLOCK;

    const float* own = dir ? x : y;
    const float* opp = dir ? y : x;

    const int t = threadIdx.x;
    const int l = t & 63;
    const int su = __builtin_amdgcn_readfirstlane(t >> 6);  // wave id

    // Zero the f64 accumulators + completion counter (one block; the reduce
    // kernel that consumes them runs strictly after this kernel).
    if (blockIdx.x == 0 && blockIdx.y == 0 && blockIdx.z == 0) {
        if (t < 2) acc[t] = 0.0;
        if (t == 2) *cnt = 0u;
    }

    // Stage opp slice into LDS in dot form: (-2qx, -2qy, -2qz, |q|^2).
    __shared__ float4 sq[OPP_SLICE];       // 4 KB
    {
        const float* ob = opp + ((size_t)b * N_ + oc * OPP_SLICE) * 3;
        const float a = ob[3 * t], bb = ob[3 * t + 1], c = ob[3 * t + 2];
        sq[t] = make_float4(-2.f * a, -2.f * bb, -2.f * c,
                            a * a + bb * bb + c * c);
    }

    // Per-lane own points (coalesced 12 B/lane per group of 64).
    const float* op0 = own + ((size_t)b * N_ + base + l) * 3;
    const float px0 = op0[0],    py0 = op0[1],    pz0 = op0[2];
    const float px1 = op0[192],  py1 = op0[193],  pz1 = op0[194];
    const float px2 = op0[384],  py2 = op0[385],  pz2 = op0[386];
    const float px3 = op0[576],  py3 = op0[577],  pz3 = op0[578];
    const float px4 = op0[768],  py4 = op0[769],  pz4 = op0[770];
    const float px5 = op0[960],  py5 = op0[961],  pz5 = op0[962];
    const float px6 = op0[1152], py6 = op0[1153], pz6 = op0[1154];
    const float px7 = op0[1344], py7 = op0[1345], pz7 = op0[1346];

    __syncthreads();

    float m0 = 1e30f, m1 = 1e30f, m2 = 1e30f, m3 = 1e30f;
    float m4 = 1e30f, m5 = 1e30f, m6 = 1e30f, m7 = 1e30f;

    // Hot loop: wave su scans its 64-pt quarter via broadcast ds_read_b128,
    // two opp points per iteration (min3 fusion).
    const float4* qs = &sq[su * OPP_PER_WAVE];
#pragma unroll 2
    for (int k = 0; k < OPP_PER_WAVE; k += 2) {
        const float4 qA = qs[k];
        const float4 qB = qs[k + 1];
        EVAL_PAIR(qA, qB, px0, py0, pz0, m0);
        EVAL_PAIR(qA, qB, px1, py1, pz1, m1);
        EVAL_PAIR(qA, qB, px2, py2, pz2, m2);
        EVAL_PAIR(qA, qB, px3, py3, pz3, m3);
        EVAL_PAIR(qA, qB, px4, py4, pz4, m4);
        EVAL_PAIR(qA, qB, px5, py5, pz5, m5);
        EVAL_PAIR(qA, qB, px6, py6, pz6, m6);
        EVAL_PAIR(qA, qB, px7, py7, pz7, m7);
    }

    // d^2 = min_e + |p|^2; cross-wave min; coalesced partial writes.
    __shared__ float red[4][OWN_PER_BLOCK]; // 8 KB
    red[su][l]       = m0 + (px0 * px0 + py0 * py0 + pz0 * pz0);
    red[su][64 + l]  = m1 + (px1 * px1 + py1 * py1 + pz1 * pz1);
    red[su][128 + l] = m2 + (px2 * px2 + py2 * py2 + pz2 * pz2);
    red[su][192 + l] = m3 + (px3 * px3 + py3 * py3 + pz3 * pz3);
    red[su][256 + l] = m4 + (px4 * px4 + py4 * py4 + pz4 * pz4);
    red[su][320 + l] = m5 + (px5 * px5 + py5 * py5 + pz5 * pz5);
    red[su][384 + l] = m6 + (px6 * px6 + py6 * py6 + pz6 * pz6);
    red[su][448 + l] = m7 + (px7 * px7 + py7 * py7 + pz7 * pz7);
    __syncthreads();

    float* pr = part + (((size_t)dir * B_ + b) * OPP_CHUNKS + oc) * N_ + base;
#pragma unroll
    for (int k = 0; k < 2; ++k) {
        const int i = k * 256 + t;
        pr[i] = fminf(fminf(red[0][i], red[1][i]), fminf(red[2][i], red[3][i]));
    }
}

// Combine OPP_CHUNKS partials, apply mask, accumulate in f64; the last block
// to finish writes the final scalar (fused finalize). Device-scope fences
// live only here (256 small blocks, after the compute).
__global__ __launch_bounds__(256) void chamfer_reduce_kernel(
        const float* __restrict__ part,
        const float* __restrict__ xm, const float* __restrict__ ym,
        double* __restrict__ acc, unsigned* __restrict__ cnt,
        float* __restrict__ out) {
    const int id  = blockIdx.x * 256 + threadIdx.x;
    const int dir = id >> 15;            // uniform per wave
    const int rem = id & 32767;
    const int b   = rem >> 12;
    const int n   = rem & (N_ - 1);

    const float* msk = dir ? ym : xm;

    float mn = 1e30f;
#pragma unroll
    for (int oc = 0; oc < OPP_CHUNKS; ++oc)
        mn = fminf(mn, part[(((size_t)dir * B_ + b) * OPP_CHUNKS + oc) * N_ + n]);

    double val = (double)(msk[(size_t)b * N_ + n] * mn);
    for (int off = 32; off; off >>= 1)
        val += __shfl_down(val, off);
    if ((threadIdx.x & 63) == 0)
        atomicAdd(&acc[dir], val);

    __syncthreads();
    if (threadIdx.x == 0) {
        __threadfence();
        unsigned old = atomicAdd(cnt, 1u);
        if (old == RED_BLOCKS - 1) {
            __threadfence();
            volatile const double* va = acc;
            double d = (va[0] - va[1]) / (double)(B_ * N_);
            out[0] = (float)(d * d);
        }
    }
}

extern "C" void kernel_launch(void* const* d_in, const int* in_sizes, int n_in,
                              void* d_out, int out_size, void* d_ws, size_t ws_size,
                              hipStream_t stream) {
    const float* x  = (const float*)d_in[0];
    const float* y  = (const float*)d_in[1];
    const float* xm = (const float*)d_in[2];
    const float* ym = (const float*)d_in[3];
    float* out = (float*)d_out;

    double*   acc = (double*)d_ws;                          // 16 B
    unsigned* cnt = (unsigned*)((char*)d_ws + 16);          // 4 B
    float*    prt = (float*)((char*)d_ws + 256);            // 2*8*16*4096*4 = 4 MB

    dim3 grid(OWN_CHUNKS, B_ * OPP_CHUNKS, 2);              // 2048 blocks
    chamfer_min_kernel<<<grid, 256, 0, stream>>>(x, y, prt, acc, cnt);

    chamfer_reduce_kernel<<<RED_BLOCKS, 256, 0, stream>>>(prt, xm, ym, acc, cnt, out);
}